// Round 2
// baseline (2015.401 us; speedup 1.0000x reference)
//
#include <hip/hip_runtime.h>
#include <hip/hip_bf16.h>

#define NB 2
#define NN 50000
#define NKK 16
#define ND 64
static constexpr float EPS = 1e-5f;

typedef __attribute__((ext_vector_type(8))) short short8;
typedef __attribute__((ext_vector_type(16))) float f32x16;
typedef unsigned int u32;

// LDS frag table offsets (in frags; 1 frag = 64 lanes * 16B = 1 KB)
#define OFF_G2 0    // 4 mt * 5 ks = 20
#define OFF_G3 20   // 2 * 9 = 18
#define OFF_F1 38   // 2 * 9 = 18
#define OFF_F2 56   // 4 * 5 = 20
#define OFF_W3 76   // 2 * 9 = 18
#define NFRAGS 94   // 94 KB LDS

__device__ __forceinline__ u32 pkbf(float a, float b) {
  u32 lo = (u32)__builtin_bit_cast(unsigned short, __float2bfloat16(a));
  u32 hi = (u32)__builtin_bit_cast(unsigned short, __float2bfloat16(b));
  return lo | (hi << 16);
}

__device__ __forceinline__ f32x16 zero16() {
  f32x16 z;
#pragma unroll
  for (int i = 0; i < 16; ++i) z[i] = 0.f;
  return z;
}

// Stage one layer's A-fragments (W^T with bias K-slot) into LDS as bf16.
// A-frag layout for mfma_f32_32x32x16_bf16: lane l holds A[row=l&31][k=8*(l>>5)+j], j=0..7.
// Here row = out_ch (mt*32 + (l&31)), k = ks*16 + 8h + j; k==IN is the bias slot.
template <int IN, int OUT, int KS>
__device__ __forceinline__ void stage(const float* __restrict__ W,
                                      const float* __restrict__ Bv,
                                      uint4* __restrict__ lds, int fragoff,
                                      float scale, int tid) {
  constexpr int MT = OUT / 32;
  constexpr int ENT = MT * KS * 64;
  for (int e = tid; e < ENT; e += 512) {
    int lane = e & 63, f = e >> 6;
    int mt = f / KS, ks = f - mt * KS;
    int h = lane >> 5, och = mt * 32 + (lane & 31);
    int k0 = ks * 16 + h * 8;
    u32 d[4];
#pragma unroll
    for (int p = 0; p < 4; ++p) {
      int ka = k0 + 2 * p, kb = ka + 1;
      float a = (ka < IN) ? W[ka * OUT + och] * scale
                          : ((ka == IN) ? Bv[och] * scale : 0.f);
      float b = (kb < IN) ? W[kb * OUT + och] * scale
                          : ((kb == IN) ? Bv[och] * scale : 0.f);
      d[p] = pkbf(a, b);
    }
    lds[(fragoff + f) * 64 + lane] = make_uint4(d[0], d[1], d[2], d[3]);
  }
}

__device__ __forceinline__ short8 rdfrag(const uint4* __restrict__ lds,
                                         int fragidx, int lane) {
  return __builtin_bit_cast(short8, lds[fragidx * 64 + lane]);
}

template <int MT, int KS>
__device__ __forceinline__ void run_layer(f32x16* acc, const short8* bfr,
                                          const uint4* __restrict__ lds,
                                          int fragoff, int lane) {
#pragma unroll
  for (int mt = 0; mt < MT; ++mt) acc[mt] = zero16();
#pragma unroll
  for (int ks = 0; ks < KS; ++ks)
#pragma unroll
    for (int mt = 0; mt < MT; ++mt)
      acc[mt] = __builtin_amdgcn_mfma_f32_32x32x16_bf16(
          rdfrag(lds, fragoff + mt * KS + ks, lane), bfr[ks], acc[mt], 0, 0, 0);
}

// Convert D-layout f32 accumulators (col=pt=lane&31, ch=(r&3)+8*(r>>2)+4h+32mt)
// into next-layer B-frags (lane l holds B[k=16t+8h+j][pt=l&31]).
// Per kstep t: regs q0..q0+7 of acc[t>>1], q0=(t&1)*8; pack pairs, 2 permlane32_swap.
template <int NK>
__device__ __forceinline__ void to_bfr(const f32x16* acc, short8* bfr) {
#pragma unroll
  for (int t = 0; t < NK; ++t) {
    constexpr_hack:;
    const int mt = t >> 1, q0 = (t & 1) * 8;
    u32 P0 = pkbf(acc[mt][q0 + 0], acc[mt][q0 + 1]);
    u32 P1 = pkbf(acc[mt][q0 + 2], acc[mt][q0 + 3]);
    u32 P2 = pkbf(acc[mt][q0 + 4], acc[mt][q0 + 5]);
    u32 P3 = pkbf(acc[mt][q0 + 6], acc[mt][q0 + 7]);
    auto s1 = __builtin_amdgcn_permlane32_swap((int)P0, (int)P2, false, false);
    auto s2 = __builtin_amdgcn_permlane32_swap((int)P1, (int)P3, false, false);
    uint4 q = make_uint4((u32)s1[0], (u32)s2[0], (u32)s1[1], (u32)s2[1]);
    bfr[t] = __builtin_bit_cast(short8, q);
  }
}

template <int MT, bool ACT>
__device__ __forceinline__ void ln_act(f32x16* acc, const float* __restrict__ gam,
                                       const float* __restrict__ bet, int lane) {
  constexpr float DIMINV = 1.f / (32.f * MT);
  float s = 0.f, q = 0.f;
#pragma unroll
  for (int mt = 0; mt < MT; ++mt)
#pragma unroll
    for (int r = 0; r < 16; ++r) {
      float v = acc[mt][r];
      s += v;
      q += v * v;
    }
  s += __shfl_xor(s, 32);
  q += __shfl_xor(q, 32);
  const float mean = s * DIMINV;
  const float inv = rsqrtf(q * DIMINV - mean * mean + EPS);
  const int h = (lane >> 5) & 1;
#pragma unroll
  for (int mt = 0; mt < MT; ++mt)
#pragma unroll
    for (int rq = 0; rq < 4; ++rq) {
      const int ch0 = 32 * mt + 8 * rq + 4 * h;
      const float4 g4 = *(const float4*)(gam + ch0);
      const float4 b4 = *(const float4*)(bet + ch0);
      const float gg[4] = {g4.x, g4.y, g4.z, g4.w};
      const float bb[4] = {b4.x, b4.y, b4.z, b4.w};
#pragma unroll
      for (int c = 0; c < 4; ++c) {
        float y = (acc[mt][4 * rq + c] - mean) * inv * gg[c] + bb[c];
        acc[mt][4 * rq + c] = ACT ? fmaxf(y, 0.2f * y) : y;
      }
    }
}

extern "C" __global__ void __launch_bounds__(512, 2)
lfa_mfma(const float* __restrict__ pf, const float* __restrict__ geom,
         const int* __restrict__ nidx,
         const float* __restrict__ g_w1, const float* __restrict__ g_b1,
         const float* __restrict__ g_ls1, const float* __restrict__ g_lb1,
         const float* __restrict__ g_w2, const float* __restrict__ g_b2,
         const float* __restrict__ g_ls2, const float* __restrict__ g_lb2,
         const float* __restrict__ g_w3, const float* __restrict__ g_b3,
         const float* __restrict__ f_w1, const float* __restrict__ f_b1,
         const float* __restrict__ f_ls1, const float* __restrict__ f_lb1,
         const float* __restrict__ f_w2, const float* __restrict__ f_b2,
         const float* __restrict__ f_ls2, const float* __restrict__ f_lb2,
         const float* __restrict__ f_w3, const float* __restrict__ f_b3,
         float* __restrict__ out) {
  extern __shared__ uint4 lds[];
  const int tid = threadIdx.x;

  stage<64, 128, 5>(g_w2, g_b2, lds, OFF_G2, 1.f, tid);
  stage<128, 64, 9>(g_w3, g_b3, lds, OFF_G3, 1.f, tid);
  stage<128, 64, 9>(f_w1, f_b1, lds, OFF_F1, 1.f, tid);
  stage<64, 128, 5>(f_w2, f_b2, lds, OFF_F2, 1.f, tid);
  stage<128, 64, 9>(f_w3, f_b3, lds, OFF_W3, 1.f / 16.f, tid);  // fold mean 1/16
  __syncthreads();

  const int lane = tid & 63;
  const int w = tid >> 6;
  const int h = lane >> 5;
  const int p31 = lane & 31;

  // gL1 (4->64, K padded to 16 with bias at k=4) A-frags in registers.
  short8 a1[2];
#pragma unroll
  for (int mt = 0; mt < 2; ++mt) {
    const int och = 32 * mt + p31;
    uint4 q;
    q.x = h ? 0u : pkbf(g_w1[0 * 64 + och], g_w1[1 * 64 + och]);
    q.y = h ? 0u : pkbf(g_w1[2 * 64 + och], g_w1[3 * 64 + och]);
    q.z = h ? 0u : pkbf(g_b1[och], 0.f);
    q.w = 0u;
    a1[mt] = __builtin_bit_cast(short8, q);
  }
  // Constant B-frag for bias K-slots: channel IN == 1.0 (bf16 1.0 = 0x3F80).
  const short8 biasfrag = __builtin_bit_cast(
      short8, make_uint4(h ? 0u : 0x00003F80u, 0u, 0u, 0u));

  for (int tile = blockIdx.x * 8 + w; tile < 50000; tile += 250 * 8) {
    const int rrow = tile * 32 + p31;
    const int bb = tile / 25000;

    // ---- geom L1 ----
    const float4 g4 = *(const float4*)(geom + (size_t)rrow * 4);
    uint4 gq;
    gq.x = h ? 0u : pkbf(g4.x, g4.y);
    gq.y = h ? 0u : pkbf(g4.z, g4.w);
    gq.z = h ? 0u : 0x00003F80u;  // 1.0 for bias slot k=4
    gq.w = 0u;
    const short8 gb = __builtin_bit_cast(short8, gq);
    f32x16 acc1[2];
#pragma unroll
    for (int mt = 0; mt < 2; ++mt)
      acc1[mt] = __builtin_amdgcn_mfma_f32_32x32x16_bf16(a1[mt], gb, zero16(), 0, 0, 0);
    ln_act<2, true>(acc1, g_ls1, g_lb1, lane);

    // ---- geom L2: 64 -> 128 ----
    short8 bfr[9];
    to_bfr<4>(acc1, bfr);
    bfr[4] = biasfrag;
    f32x16 acc2[4];
    run_layer<4, 5>(acc2, bfr, lds, OFF_G2, lane);
    ln_act<4, true>(acc2, g_ls2, g_lb2, lane);

    // ---- geom L3: 128 -> 64 (no LN/act) ----
    to_bfr<8>(acc2, bfr);
    bfr[8] = biasfrag;
    f32x16 acc3[2];
    run_layer<2, 9>(acc3, bfr, lds, OFF_G3, lane);

    // ---- feature L1: concat(geom_out, gathered pf) 128 -> 64 ----
    to_bfr<4>(acc3, bfr);
    {
      const int idx = nidx[rrow];
      const float* prow = pf + ((size_t)bb * NN + idx) * ND;
#pragma unroll
      for (int t = 0; t < 4; ++t) {
        const float4 x = *(const float4*)(prow + 16 * t + 8 * h);
        const float4 y = *(const float4*)(prow + 16 * t + 8 * h + 4);
        uint4 fq;
        fq.x = pkbf(x.x, x.y);
        fq.y = pkbf(x.z, x.w);
        fq.z = pkbf(y.x, y.y);
        fq.w = pkbf(y.z, y.w);
        bfr[4 + t] = __builtin_bit_cast(short8, fq);
      }
    }
    bfr[8] = biasfrag;
    f32x16 acc4[2];
    run_layer<2, 9>(acc4, bfr, lds, OFF_F1, lane);
    ln_act<2, true>(acc4, f_ls1, f_lb1, lane);

    // ---- feature L2: 64 -> 128 ----
    to_bfr<4>(acc4, bfr);
    bfr[4] = biasfrag;
    f32x16 acc5[4];
    run_layer<4, 5>(acc5, bfr, lds, OFF_F2, lane);
    ln_act<4, true>(acc5, f_ls2, f_lb2, lane);

    // ---- final 128 -> 64 with mean folded (w3,b3 pre-scaled 1/16) ----
    to_bfr<8>(acc5, bfr);
    bfr[8] = biasfrag;
    f32x16 acc6[2];
    run_layer<2, 9>(acc6, bfr, lds, OFF_W3, lane);

    // sum over the 16 k-columns of each bn group
#pragma unroll
    for (int mt = 0; mt < 2; ++mt)
#pragma unroll
      for (int r = 0; r < 16; ++r) {
        float v = acc6[mt][r];
        v += __shfl_xor(v, 1);
        v += __shfl_xor(v, 2);
        v += __shfl_xor(v, 4);
        v += __shfl_xor(v, 8);
        acc6[mt][r] = v;
      }
    if ((lane & 15) < 4) {
      const int c = lane & 15;
      const int bn = (lane >> 4) & 1;
      const size_t row = (size_t)tile * 2 + bn;
#pragma unroll
      for (int mt = 0; mt < 2; ++mt) {
        const float4 v =
            (c == 0) ? make_float4(acc6[mt][0], acc6[mt][1], acc6[mt][2], acc6[mt][3])
          : (c == 1) ? make_float4(acc6[mt][4], acc6[mt][5], acc6[mt][6], acc6[mt][7])
          : (c == 2) ? make_float4(acc6[mt][8], acc6[mt][9], acc6[mt][10], acc6[mt][11])
                     : make_float4(acc6[mt][12], acc6[mt][13], acc6[mt][14], acc6[mt][15]);
        *(float4*)(out + row * 64 + 32 * mt + 8 * c + 4 * h) = v;
      }
    }
  }
}

extern "C" void kernel_launch(void* const* d_in, const int* in_sizes, int n_in,
                              void* d_out, int out_size, void* d_ws, size_t ws_size,
                              hipStream_t stream) {
  const float* pf = (const float*)d_in[0];
  const float* geom = (const float*)d_in[1];
  const int* nidx = (const int*)d_in[2];
  const float* g_w1 = (const float*)d_in[3];
  const float* g_b1 = (const float*)d_in[4];
  const float* g_ls1 = (const float*)d_in[5];
  const float* g_lb1 = (const float*)d_in[6];
  const float* g_w2 = (const float*)d_in[7];
  const float* g_b2 = (const float*)d_in[8];
  const float* g_ls2 = (const float*)d_in[9];
  const float* g_lb2 = (const float*)d_in[10];
  const float* g_w3 = (const float*)d_in[11];
  const float* g_b3 = (const float*)d_in[12];
  const float* f_w1 = (const float*)d_in[13];
  const float* f_b1 = (const float*)d_in[14];
  const float* f_ls1 = (const float*)d_in[15];
  const float* f_lb1 = (const float*)d_in[16];
  const float* f_w2 = (const float*)d_in[17];
  const float* f_b2 = (const float*)d_in[18];
  const float* f_ls2 = (const float*)d_in[19];
  const float* f_lb2 = (const float*)d_in[20];
  const float* f_w3 = (const float*)d_in[21];
  const float* f_b3 = (const float*)d_in[22];

  const int shmem = NFRAGS * 64 * 16;  // 96256 B
  lfa_mfma<<<250, 512, shmem, stream>>>(
      pf, geom, nidx, g_w1, g_b1, g_ls1, g_lb1, g_w2, g_b2, g_ls2, g_lb2, g_w3,
      g_b3, f_w1, f_b1, f_ls1, f_lb1, f_w2, f_b2, f_ls2, f_lb2, f_w3, f_b3,
      (float*)d_out);
}